// Round 11
// baseline (188.946 us; speedup 1.0000x reference)
//
#include <hip/hip_runtime.h>
#include <math.h>

#define BATCH 4
#define SEQ   2048
#define DM    1024
#define NTOK  (BATCH * SEQ)   // 8192

typedef __attribute__((ext_vector_type(8))) short bf16x8;
typedef __attribute__((ext_vector_type(4))) float f32x4;
typedef unsigned short u16;
struct alignas(8) us4 { u16 x, y, z, w; };

__device__ __forceinline__ u16 f2bf(float f) {
    union { float f; unsigned u; } v; v.f = f;
    unsigned r = v.u + 0x7fffu + ((v.u >> 16) & 1u);   // round-to-nearest-even
    return (u16)(r >> 16);
}

__device__ __forceinline__ void gload_lds16(const void* g, void* l) {
    __builtin_amdgcn_global_load_lds(
        (const __attribute__((address_space(1))) unsigned int*)g,
        (__attribute__((address_space(3))) unsigned int*)l, 16, 0, 0);
}

// ===========================================================================
// 8-phase 256x128 qkv GEMM (T2+T3+T4+T5).
// A tile [256][64] bf16 (2 halves of 128 rows); B tile [128][64] (2 halves of
// 64 rows). LDS linear; reads XOR-swizzled byte^=(row&7)<<4; gload_lds source
// carries the inverse swizzle (rule #21: linear dest + swz source + swz read).
// ===========================================================================

// stage one A-half (2 gload_lds16/thread, 16 KB). Dest base wave-uniform.
__device__ __forceinline__ void stageA(const u16* __restrict__ G, int ld,
    int row0, int kt, u16* Ab, int h, int wid, int lane)
{
    #pragma unroll
    for (int rr = 0; rr < 2; ++rr) {
        const int base = h * 16384 + rr * 8192 + wid * 1024;  // dest byte
        const int off  = base + lane * 16;
        const int row  = off >> 7;                            // 0..255
        const int cbs  = (off & 127) ^ ((row & 7) << 4);      // swz source col
        gload_lds16(G + (size_t)(row0 + row) * ld + kt + (cbs >> 1),
                    (char*)Ab + base);
    }
}
// stage one B-half (1 gload_lds16/thread, 8 KB)
__device__ __forceinline__ void stageB(const u16* __restrict__ G, int ld,
    int row0, int kt, u16* Bb, int h, int wid, int lane)
{
    const int base = h * 8192 + wid * 1024;
    const int off  = base + lane * 16;
    const int row  = off >> 7;                                // 0..127
    const int cbs  = (off & 127) ^ ((row & 7) << 4);
    gload_lds16(G + (size_t)(row0 + row) * ld + kt + (cbs >> 1),
                (char*)Bb + base);
}

struct Frags { bf16x8 a[2][4]; bf16x8 b[2]; };

// Quadrant (MH = A-half, NH = B-half/g). Wave: wr = M-half interleave
// (global m-frag = 2f+wr), wc = N interleave (global n-frag = 4g+wc).
template<int MH, int NH>
__device__ __forceinline__ Frags phase_read(const u16* As, const u16* Bs,
                                            int wr, int wc, int lane)
{
    Frags fr;
    const int lrow = lane & 15, lhi = lane >> 4, sw = (lane & 7) << 4;
    #pragma unroll
    for (int kk = 0; kk < 2; ++kk) {
        const int cb = (kk * 64 + lhi * 16) ^ sw;
        #pragma unroll
        for (int fi = 0; fi < 4; ++fi) {
            const int row = (2 * (MH * 4 + fi) + wr) * 16 + lrow;
            fr.a[kk][fi] = *(const bf16x8*)(As + row * 64 + (cb >> 1));
        }
        const int nrow = (4 * NH + wc) * 16 + lrow;
        fr.b[kk] = *(const bf16x8*)(Bs + nrow * 64 + (cb >> 1));
    }
    return fr;
}

template<int MH, int NH>
__device__ __forceinline__ void phase_fma(const Frags& fr, f32x4 acc[8][2])
{
    __builtin_amdgcn_s_setprio(1);
    #pragma unroll
    for (int fi = 0; fi < 4; ++fi)
        #pragma unroll
        for (int kk = 0; kk < 2; ++kk)
            acc[MH * 4 + fi][NH] = __builtin_amdgcn_mfma_f32_16x16x32_bf16(
                fr.a[kk][fi], fr.b[kk], acc[MH * 4 + fi][NH], 0, 0, 0);
    __builtin_amdgcn_s_setprio(0);
}

#define VM3 asm volatile("s_waitcnt vmcnt(3)" ::: "memory")
#define VM0 asm volatile("s_waitcnt vmcnt(0)" ::: "memory")
#define BAR __builtin_amdgcn_s_barrier()

__global__ __launch_bounds__(512) void qkv_mfma8(
    const u16* __restrict__ xb,
    const u16* __restrict__ wqb, const float* __restrict__ bq,
    const u16* __restrict__ wkb, const float* __restrict__ bk,
    const u16* __restrict__ wvb, const float* __restrict__ bv,
    u16* __restrict__ qb, u16* __restrict__ kb, u16* __restrict__ vT)
{
    __shared__ u16 As0[256 * 64], As1[256 * 64];   // 32 KB each
    __shared__ u16 Bs0[128 * 64], Bs1[128 * 64];   // 16 KB each

    const int z = blockIdx.z;
    const u16* W = (z == 0) ? wqb : (z == 1) ? wkb : wvb;
    const float* bias = (z == 0) ? bq : (z == 1) ? bk : bv;
    const int m0 = blockIdx.x * 256;
    const int n0 = blockIdx.y * 128;                // within this z's 1024
    const int t = threadIdx.x, wid = t >> 6, lane = t & 63;
    const int wr = wid >> 2, wc = wid & 3;

    f32x4 acc[8][2] = {};

    // prologue: tile0 all halves + tile1 {A0,B0}  (9 loads) -> vmcnt(3)
    stageA(xb, DM, m0, 0,  As0, 0, wid, lane);
    stageB(W,  DM, n0, 0,  Bs0, 0, wid, lane);
    stageA(xb, DM, m0, 0,  As0, 1, wid, lane);
    stageB(W,  DM, n0, 0,  Bs0, 1, wid, lane);
    stageA(xb, DM, m0, 64, As1, 0, wid, lane);
    stageB(W,  DM, n0, 64, Bs1, 0, wid, lane);
    VM3;
    BAR;

    #pragma unroll 1
    for (int i = 0; i < 8; ++i) {
        const int kb2 = i * 128 + 64, k2 = i * 128 + 128, k3 = i * 128 + 192;
        const bool s2 = (k2 < 1024), s3 = (k3 < 1024);
        // ph0: buf0 (A0,B0); stage buf1.A1 <- tile b (always valid)
        { Frags fr = phase_read<0,0>(As0, Bs0, wr, wc, lane);
          stageA(xb, DM, m0, kb2, As1, 1, wid, lane);
          BAR; phase_fma<0,0>(fr, acc); BAR; }
        // ph1: (A0,B1); stage buf1.B1 <- b
        { Frags fr = phase_read<0,1>(As0, Bs0, wr, wc, lane);
          stageB(W, DM, n0, kb2, Bs1, 1, wid, lane);
          BAR; phase_fma<0,1>(fr, acc); BAR; }
        // ph2: (A1,B0); stage buf0.A0 <- t+2
        { Frags fr = phase_read<1,0>(As0, Bs0, wr, wc, lane);
          if (s2) stageA(xb, DM, m0, k2, As0, 0, wid, lane);
          BAR; phase_fma<1,0>(fr, acc); BAR; }
        // ph3: (A1,B1); stage buf0.B0 <- t+2 ; counted vmcnt
        { Frags fr = phase_read<1,1>(As0, Bs0, wr, wc, lane);
          if (s2) { stageB(W, DM, n0, k2, Bs0, 0, wid, lane); VM3; }
          else    { VM0; }
          BAR; phase_fma<1,1>(fr, acc); BAR; }
        // ph4: buf1 (A0,B0); stage buf0.A1 <- t+2
        { Frags fr = phase_read<0,0>(As1, Bs1, wr, wc, lane);
          if (s2) stageA(xb, DM, m0, k2, As0, 1, wid, lane);
          BAR; phase_fma<0,0>(fr, acc); BAR; }
        // ph5: (A0,B1); stage buf0.B1 <- t+2
        { Frags fr = phase_read<0,1>(As1, Bs1, wr, wc, lane);
          if (s2) stageB(W, DM, n0, k2, Bs0, 1, wid, lane);
          BAR; phase_fma<0,1>(fr, acc); BAR; }
        // ph6: (A1,B0); stage buf1.A0 <- t+3
        { Frags fr = phase_read<1,0>(As1, Bs1, wr, wc, lane);
          if (s3) stageA(xb, DM, m0, k3, As1, 0, wid, lane);
          BAR; phase_fma<1,0>(fr, acc); BAR; }
        // ph7: (A1,B1); stage buf1.B0 <- t+3 ; counted vmcnt
        { Frags fr = phase_read<1,1>(As1, Bs1, wr, wc, lane);
          if (s3) { stageB(W, DM, n0, k3, Bs1, 0, wid, lane); VM3; }
          else    { VM0; }
          BAR; phase_fma<1,1>(fr, acc); BAR; }
    }

    // epilogue: C/D col=lane&15, row=(lane>>4)*4+r per 16x16 frag
    const int lrow = lane & 15, lhi = lane >> 4;
    if (z < 2) {
        u16* outp = (z == 0) ? qb : kb;
        #pragma unroll
        for (int g = 0; g < 2; ++g) {
            const int n = n0 + (4 * g + wc) * 16 + lrow;
            const float bn = bias[n];
            #pragma unroll
            for (int f = 0; f < 8; ++f) {
                const int mb = m0 + (2 * f + wr) * 16 + lhi * 4;
                #pragma unroll
                for (int r = 0; r < 4; ++r)
                    outp[(size_t)(mb + r) * DM + n] = f2bf(acc[f][g][r] + bn);
            }
        }
    } else {
        #pragma unroll
        for (int g = 0; g < 2; ++g) {
            const int n = n0 + (4 * g + wc) * 16 + lrow;
            const float bn = bias[n];
            #pragma unroll
            for (int f = 0; f < 8; ++f) {
                const int mb = m0 + (2 * f + wr) * 16 + lhi * 4;
                us4 p{f2bf(acc[f][g][0] + bn), f2bf(acc[f][g][1] + bn),
                      f2bf(acc[f][g][2] + bn), f2bf(acc[f][g][3] + bn)};
                *(us4*)(vT + (size_t)n * NTOK + mb) = p;   // transposed store
            }
        }
    }
}

// ===========================================================================
// unchanged R9 kernels below
// ===========================================================================

// Stage a 128-row x 32-k bf16 tile into linear LDS [128][32].
__device__ __forceinline__ void stage_tile(
    const u16* __restrict__ G, int ld, int row0, int kt,
    u16* lds, int wid, int lane)
{
    #pragma unroll
    for (int j = 0; j < 2; ++j) {
        const int off  = wid * 2048 + j * 1024;
        const int loff = off + lane * 16;
        const int row  = loff >> 6;
        const int ke   = (loff & 63) >> 1;
        gload_lds16(G + (size_t)(row0 + row) * ld + kt + ke, (char*)lds + off);
    }
}

__device__ __forceinline__ void frag_mma(
    const u16* As, const u16* Bs, int wr, int wc, int lane, f32x4 acc[4][4])
{
    const int lrow = lane & 15, lk = (lane >> 4) * 8;
    bf16x8 a[4], b[4];
    #pragma unroll
    for (int i = 0; i < 4; ++i)
        a[i] = *(const bf16x8*)(As + (wr * 64 + i * 16 + lrow) * 32 + lk);
    #pragma unroll
    for (int i = 0; i < 4; ++i)
        b[i] = *(const bf16x8*)(Bs + (wc * 64 + i * 16 + lrow) * 32 + lk);
    #pragma unroll
    for (int i = 0; i < 4; ++i)
        #pragma unroll
        for (int j = 0; j < 4; ++j)
            acc[i][j] = __builtin_amdgcn_mfma_f32_16x16x32_bf16(
                a[i], b[j], acc[i][j], 0, 0, 0);
}

__global__ __launch_bounds__(256) void conv_all(
    const float* __restrict__ x,
    const float* __restrict__ w0, const float* __restrict__ w1,
    const float* __restrict__ w2,
    u16* __restrict__ xo,
    u16* __restrict__ o0, u16* __restrict__ o1, u16* __restrict__ o2)
{
    const int z = blockIdx.z;
    const float* in = (z == 0) ? x : (z == 1) ? w0 : (z == 2) ? w1 : w2;
    u16* out = (z == 0) ? xo : (z == 1) ? o0 : (z == 2) ? o1 : o2;
    const int n4 = (z == 0) ? (NTOK * DM / 4) : (DM * DM / 4);
    for (int i = blockIdx.x * 256 + threadIdx.x; i < n4; i += gridDim.x * 256) {
        float4 f = ((const float4*)in)[i];
        us4 p{f2bf(f.x), f2bf(f.y), f2bf(f.z), f2bf(f.w)};
        ((us4*)out)[i] = p;
    }
}

__global__ __launch_bounds__(256, 3) void qk_exp(
    const u16* __restrict__ qb, const u16* __restrict__ kb,
    u16* __restrict__ attn, float* __restrict__ psum)
{
    const int m0 = blockIdx.x * 128, n0 = blockIdx.y * 128;
    if (n0 > m0) return;
    __shared__ u16 As[128 * 32], Bs[128 * 32];
    const int b = blockIdx.z;
    const u16* A = qb + (size_t)b * SEQ * DM;
    const u16* B = kb + (size_t)b * SEQ * DM;
    u16* P = attn + (size_t)b * SEQ * SEQ;
    const int t = threadIdx.x, wid = t >> 6, lane = t & 63;
    const int wr = wid >> 1, wc = wid & 1;

    f32x4 acc[4][4] = {};
    for (int kt = 0; kt < DM; kt += 32) {
        __syncthreads();
        stage_tile(A, DM, m0, kt, As, wid, lane);
        stage_tile(B, DM, n0, kt, Bs, wid, lane);
        __syncthreads();
        frag_mma(As, Bs, wr, wc, lane, acc);
    }
    const int lrow = lane & 15, lg = lane >> 4;
    const float scale = 0.03125f;
    const int nb = (n0 >> 6) | wc;
    #pragma unroll
    for (int mi = 0; mi < 4; ++mi) {
        #pragma unroll
        for (int r = 0; r < 4; ++r) {
            const int row = m0 + wr * 64 + mi * 16 + lg * 4 + r;
            float ps = 0.f;
            #pragma unroll
            for (int ni = 0; ni < 4; ++ni) {
                const int n = n0 + wc * 64 + ni * 16 + lrow;
                const float p = (n <= row) ? __expf(acc[mi][ni][r] * scale) : 0.f;
                P[(size_t)row * SEQ + n] = f2bf(p);
                ps += p;
            }
            #pragma unroll
            for (int mk = 1; mk < 16; mk <<= 1) ps += __shfl_xor(ps, mk);
            if (lrow == 0)
                psum[((size_t)b * SEQ + row) * 32 + nb] = ps;
        }
    }
}

__global__ __launch_bounds__(256, 3) void pv_mfma(
    const u16* __restrict__ attn, const u16* __restrict__ vT,
    const float* __restrict__ psum, float* __restrict__ out)
{
    __shared__ u16 As[128 * 32], Bs[128 * 32];
    __shared__ float invs[128];
    const int m0 = blockIdx.x * 128, n0 = blockIdx.y * 128;
    const int b = blockIdx.z;
    const u16* A = attn + (size_t)b * SEQ * SEQ;
    const u16* B = vT + (size_t)b * SEQ;
    float* C = out + (size_t)b * SEQ * DM;
    const int t = threadIdx.x, wid = t >> 6, lane = t & 63;
    const int wr = wid >> 1, wc = wid & 1;

    if (t < 128) {
        const int row = m0 + t;
        const float* pr = psum + ((size_t)b * SEQ + row) * 32;
        const int nbmax = (row >> 6) | 1;
        float s = 0.f;
        for (int nbi = 0; nbi <= nbmax; ++nbi) s += pr[nbi];
        invs[t] = 1.f / s;
    }

    f32x4 acc[4][4] = {};
    const int kmax = m0 + 128;
    for (int kt = 0; kt < kmax; kt += 32) {
        __syncthreads();
        stage_tile(A, SEQ,  m0, kt, As, wid, lane);
        stage_tile(B, NTOK, n0, kt, Bs, wid, lane);
        __syncthreads();
        frag_mma(As, Bs, wr, wc, lane, acc);
    }
    const int lrow = lane & 15, lg = lane >> 4;
    #pragma unroll
    for (int mi = 0; mi < 4; ++mi) {
        const int ml = wr * 64 + mi * 16 + lg * 4;
        #pragma unroll
        for (int ni = 0; ni < 4; ++ni) {
            const int n = n0 + wc * 64 + ni * 16 + lrow;
            #pragma unroll
            for (int r = 0; r < 4; ++r)
                C[(size_t)(m0 + ml + r) * DM + n] = acc[mi][ni][r] * invs[ml + r];
        }
    }
}

// ---------------------------------------------------------------------------
extern "C" void kernel_launch(void* const* d_in, const int* in_sizes, int n_in,
                              void* d_out, int out_size, void* d_ws, size_t ws_size,
                              hipStream_t stream)
{
    const float* x  = (const float*)d_in[0];
    const float* wq = (const float*)d_in[1];
    const float* bq = (const float*)d_in[2];
    const float* wk = (const float*)d_in[3];
    const float* bk = (const float*)d_in[4];
    const float* wv = (const float*)d_in[5];
    const float* bv = (const float*)d_in[6];
    float* out = (float*)d_out;

    u16* ws  = (u16*)d_ws;
    u16* xb  = ws;
    u16* wqb = xb  + (size_t)NTOK * DM;
    u16* wkb = wqb + (size_t)DM * DM;
    u16* wvb = wkb + (size_t)DM * DM;
    u16* qb  = wvb + (size_t)DM * DM;
    u16* kb  = qb  + (size_t)NTOK * DM;
    u16* vT  = kb  + (size_t)NTOK * DM;        // [DM][NTOK]
    u16* attn = vT + (size_t)NTOK * DM;        // bf16 [B][SEQ][SEQ]
    float* psum = (float*)(attn + (size_t)BATCH * SEQ * SEQ);

    conv_all<<<dim3(512, 1, 4), 256, 0, stream>>>(
        x, wq, wk, wv, xb, wqb, wkb, wvb);

    qkv_mfma8<<<dim3(NTOK / 256, 8, 3), 512, 0, stream>>>(
        xb, wqb, bq, wkb, bk, wvb, bv, qb, kb, vT);

    qk_exp<<<dim3(SEQ / 128, SEQ / 128, BATCH), 256, 0, stream>>>(
        qb, kb, attn, psum);

    pv_mfma<<<dim3(SEQ / 128, DM / 128, BATCH), 256, 0, stream>>>(
        attn, vT, psum, out);
}